// Round 14
// baseline (328.911 us; speedup 1.0000x reference)
//
#include <hip/hip_runtime.h>

#define D 128
#define NBUK 4        // dst-range buckets for fill write locality
#define NCHF 128      // edge chunks per relation (hist/pc granularity)
#define FILL_FINE 1024
#define MAXT 4        // max row-tiles (64 rows) per block in fused MLP
#define FUSE_GX 256   // fused grid.x (x2 relations = 512 blocks = 2/CU exactly)
static constexpr float BN_EPS = 1e-5f;

typedef __attribute__((ext_vector_type(8))) short short8;
typedef __attribute__((ext_vector_type(4))) float f32x4;

// ---------------------------------------------------------------------------
// bf16 helpers (RNE)
// ---------------------------------------------------------------------------
__device__ __forceinline__ unsigned short f2bf(float f)
{
    unsigned u = __builtin_bit_cast(unsigned, f);
    unsigned r = u + 0x7fffu + ((u >> 16) & 1u);
    return (unsigned short)(r >> 16);
}
__device__ __forceinline__ float bflo(unsigned u)
{
    return __builtin_bit_cast(float, u << 16);
}
__device__ __forceinline__ float bfhi(unsigned u)
{
    return __builtin_bit_cast(float, u & 0xffff0000u);
}

// ---------------------------------------------------------------------------
// Param bundles (by value; blockIdx.y selects relation).
// ---------------------------------------------------------------------------
struct CsrRel {
    const int* src; const int* dst;
    int* counts; int* offsets; int* bsum; int* perm;
    unsigned char* rank8; unsigned* pc;
    int E; int N; int nscan;
};
struct GatherRel {
    const unsigned short* hb;
    const unsigned short* hbd;
    const int* offsets; const int* perm;
    unsigned short* x; int N;
};
struct FusedRel {
    const unsigned short* X;     // gathered x (bf16)
    const unsigned short* Wt1;   // W1^T bf16 [n][k]
    const unsigned short* Wt2;   // W2^T bf16
    const float* g1; const float* b1; const float* g2; const float* b2;
    float* st;                   // [sum1, sq1, sum2, sq2] x D (zeroed)
    float* out;                  // f32 output
    int N; int ntiles;
};

// ---------------------------------------------------------------------------
// Fused prep: blocks 0..63 weights; block 64 zeroes stats + barrier counters;
// blocks 65.. convert h tables to bf16.
// ---------------------------------------------------------------------------
__global__ __launch_bounds__(256) void prep_kernel(
    const float* __restrict__ hu, const float* __restrict__ hi,
    unsigned short* __restrict__ bu, unsigned short* __restrict__ bi8,
    int nu8, int ni8,
    const float* __restrict__ Wa, const float* __restrict__ Wb,
    const float* __restrict__ Wc, const float* __restrict__ Wd,
    unsigned short* __restrict__ wt, float* __restrict__ stats,
    int* __restrict__ bar)
{
    const int t = threadIdx.x;
    if (blockIdx.x < 64) {
        const int wsel = blockIdx.x >> 4;
        const float* W = wsel == 0 ? Wa : wsel == 1 ? Wb : wsel == 2 ? Wc : Wd;
        unsigned short* out = wt + (size_t)wsel * D * D;
        const int tile = blockIdx.x & 15;
        const int k0 = (tile >> 2) * 32, n0 = (tile & 3) * 32;
        __shared__ float s[32][33];
        const int r = t >> 3, c = (t & 7) * 4;
        float4 v = *reinterpret_cast<const float4*>(W + (size_t)(k0 + r) * D + n0 + c);
        s[r][c] = v.x; s[r][c + 1] = v.y; s[r][c + 2] = v.z; s[r][c + 3] = v.w;
        __syncthreads();
        unsigned lo = (unsigned)f2bf(s[c][r]) | ((unsigned)f2bf(s[c + 1][r]) << 16);
        unsigned hi = (unsigned)f2bf(s[c + 2][r]) | ((unsigned)f2bf(s[c + 3][r]) << 16);
        *reinterpret_cast<uint2*>(out + (size_t)(n0 + r) * D + k0 + c) =
            make_uint2(lo, hi);
        return;
    }
    if (blockIdx.x == 64) {
        reinterpret_cast<float4*>(stats)[t] = make_float4(0.f, 0.f, 0.f, 0.f);
        if (t < 8) bar[t] = 0;
        return;
    }
    int i = (blockIdx.x - 65) * 256 + t;
    if (i >= nu8 + ni8) return;
    const float* s; unsigned short* d; int o;
    if (i < nu8) { s = hu; d = bu; o = i; }
    else         { s = hi; d = bi8; o = i - nu8; }
    float4 v0 = reinterpret_cast<const float4*>(s)[o * 2];
    float4 v1 = reinterpret_cast<const float4*>(s)[o * 2 + 1];
    uint4 r;
    r.x = (unsigned)f2bf(v0.x) | ((unsigned)f2bf(v0.y) << 16);
    r.y = (unsigned)f2bf(v0.z) | ((unsigned)f2bf(v0.w) << 16);
    r.z = (unsigned)f2bf(v1.x) | ((unsigned)f2bf(v1.y) << 16);
    r.w = (unsigned)f2bf(v1.z) | ((unsigned)f2bf(v1.w) << 16);
    reinterpret_cast<uint4*>(d)[o] = r;
}

// ---------------------------------------------------------------------------
// CSR pass A: full-range u8x4-packed LDS histogram (dynamic LDS).
// ---------------------------------------------------------------------------
__global__ __launch_bounds__(256) void hist_kernel(CsrRel r0, CsrRel r1)
{
    CsrRel r = blockIdx.y ? r1 : r0;
    extern __shared__ unsigned h4[];
    const int t = threadIdx.x;
    const int c = blockIdx.x;
    const int CE = (r.E + NCHF - 1) / NCHF;
    const int e0 = c * CE;
    const int e1 = min(e0 + CE, r.E);
    const int bw4 = (r.N + 3) >> 2;

    for (int i = t; i < bw4; i += 256) h4[i] = 0u;
    __syncthreads();
    for (int e = e0 + t; e < e1; e += 256) {
        int d = r.dst[e];
        unsigned sh = (unsigned)(d & 3) * 8u;
        unsigned old = atomicAdd(&h4[d >> 2], 1u << sh);
        r.rank8[e] = (unsigned char)((old >> sh) & 0xffu);
    }
    __syncthreads();
    unsigned* out = r.pc + (size_t)c * bw4;
    for (int i = t; i < bw4; i += 256) out[i] = h4[i];
}

// ---------------------------------------------------------------------------
// CSR pass B: per-dst exclusive chunk-prefix (u8x4 lanes), totals -> counts,
// block partial -> bsum.
// ---------------------------------------------------------------------------
__global__ __launch_bounds__(256) void chunkpfx_kernel(CsrRel r0, CsrRel r1)
{
    CsrRel r = blockIdx.y ? r1 : r0;
    __shared__ unsigned lds[NCHF * 256];   // 128 KB
    const int t = threadIdx.x;
    const int j = blockIdx.x * 256 + t;
    const int bw4 = (r.N + 3) >> 2;
    int s = 0;
    if (j < bw4) {
        const unsigned* base = r.pc + j;
#pragma unroll 4
        for (int c = 0; c < NCHF; ++c)
            lds[c * 256 + t] = base[(size_t)c * bw4];
        unsigned s0 = 0, s1 = 0, s2 = 0, s3 = 0;
        for (int c = 0; c < NCHF; ++c) {
            unsigned v = lds[c * 256 + t];
            lds[c * 256 + t] = s0 | (s1 << 8) | (s2 << 16) | (s3 << 24);
            s0 += v & 0xffu;
            s1 += (v >> 8) & 0xffu;
            s2 += (v >> 16) & 0xffu;
            s3 += v >> 24;
        }
        unsigned* wb = r.pc + j;
#pragma unroll 4
        for (int c = 0; c < NCHF; ++c)
            wb[(size_t)c * bw4] = lds[c * 256 + t];
        int d0 = 4 * j;
        r.counts[d0] = (int)s0;
        if (d0 + 1 < r.N) r.counts[d0 + 1] = (int)s1;
        if (d0 + 2 < r.N) r.counts[d0 + 2] = (int)s2;
        if (d0 + 3 < r.N) r.counts[d0 + 3] = (int)s3;
        s = (int)(s0 + s1 + s2 + s3);
    }
    __shared__ int red[256];
    red[t] = s;
    __syncthreads();
    for (int off = 128; off > 0; off >>= 1) {
        if (t < off) red[t] += red[t + off];
        __syncthreads();
    }
    if (t == 0) r.bsum[blockIdx.x] = red[0];
}

// ---------------------------------------------------------------------------
// Offsets: inline <=64-entry partial scan + per-block 1024-dst scan.
// ---------------------------------------------------------------------------
__global__ __launch_bounds__(256) void scan_offsets_kernel(CsrRel rr0, CsrRel rr1)
{
    CsrRel r = blockIdx.y ? rr1 : rr0;
    if ((int)blockIdx.x >= r.nscan) return;
    __shared__ int pb[64];
    __shared__ int part[256];
    const int t = threadIdx.x;
    if (t == 0) {
        int run = 0;
        for (int i = 0; i < r.nscan; ++i) { pb[i] = run; run += r.bsum[i]; }
    }
    const int d0 = blockIdx.x * 1024 + t * 4;
    int v0 = 0, v1 = 0, v2 = 0, v3 = 0;
    if (d0 + 3 < r.N) {
        int4 q = *reinterpret_cast<const int4*>(r.counts + d0);
        v0 = q.x; v1 = q.y; v2 = q.z; v3 = q.w;
    } else {
        if (d0 < r.N) v0 = r.counts[d0];
        if (d0 + 1 < r.N) v1 = r.counts[d0 + 1];
        if (d0 + 2 < r.N) v2 = r.counts[d0 + 2];
        if (d0 + 3 < r.N) v3 = r.counts[d0 + 3];
    }
    int s = v0 + v1 + v2 + v3;
    part[t] = s;
    __syncthreads();
    for (int off = 1; off < 256; off <<= 1) {
        int tmp = (t >= off) ? part[t - off] : 0;
        __syncthreads();
        part[t] += tmp;
        __syncthreads();
    }
    int excl = part[t] - s + pb[blockIdx.x];
    int o0 = excl, o1 = o0 + v0, o2 = o1 + v1, o3 = o2 + v2;
    if (d0 + 3 < r.N) {
        *reinterpret_cast<int4*>(r.offsets + d0) = make_int4(o0, o1, o2, o3);
    } else {
        if (d0 < r.N) r.offsets[d0] = o0;
        if (d0 + 1 < r.N) r.offsets[d0 + 1] = o1;
        if (d0 + 2 < r.N) r.offsets[d0 + 2] = o2;
        if (d0 + 3 < r.N) r.offsets[d0 + 3] = o3;
    }
    if (d0 < r.N && d0 + 4 >= r.N) r.offsets[r.N] = excl + s;
}

// ---------------------------------------------------------------------------
// CSR pass C: perm fill, no atomics, NBUK dst buckets, fine blocks.
// ---------------------------------------------------------------------------
__global__ __launch_bounds__(256) void fill_kernel(CsrRel rr0, CsrRel rr1)
{
    CsrRel r = blockIdx.y ? rr1 : rr0;
    const int b = blockIdx.x & (NBUK - 1);
    const int fc = blockIdx.x >> 2;
    const int f0 = fc * FILL_FINE;
    if (f0 >= r.E) return;
    const int f1 = min(f0 + FILL_FINE, r.E);
    const int bw = (r.N + NBUK - 1) / NBUK;
    const int lo = b * bw;
    const int hi = min(lo + bw, r.N);
    const int CE = (r.E + NCHF - 1) / NCHF;
    const int c0 = f0 / CE;
    const int cb = (c0 + 1) * CE;
    const int bw4 = (r.N + 3) >> 2;
    const unsigned* pcb0 = r.pc + (size_t)c0 * bw4;
    const unsigned* pcb1 = pcb0 + bw4;
    for (int e = f0 + threadIdx.x; e < f1; e += 256) {
        int d = r.dst[e];
        if (d >= lo && d < hi) {
            const unsigned* pcc = (e >= cb) ? pcb1 : pcb0;
            unsigned sh = (unsigned)(d & 3) * 8u;
            int px = (int)((pcc[d >> 2] >> sh) & 0xffu);
            r.perm[r.offsets[d] + px + (int)r.rank8[e]] = r.src[e];
        }
    }
}

// ---------------------------------------------------------------------------
// Gather-aggregate, all-bf16 reads: x[row] = hbd[row] + sum hb[perm[i]].
// ---------------------------------------------------------------------------
__global__ __launch_bounds__(256) void gather_agg_kernel(GatherRel g0, GatherRel g1)
{
    GatherRel g = blockIdx.y ? g1 : g0;
    int row = blockIdx.x * 4 + (threadIdx.x >> 6);
    row = __builtin_amdgcn_readfirstlane(row);
    if (row >= g.N) return;
    const int c = (threadIdx.x & 63) * 2;
    const int beg = g.offsets[row], end = g.offsets[row + 1];
    unsigned us = *reinterpret_cast<const unsigned*>(g.hbd + (size_t)row * D + c);
    float2 acc = make_float2(bflo(us), bfhi(us));
    const unsigned short* hb = g.hb;
    int i = beg;
    for (; i + 7 < end; i += 8) {
        unsigned u[8];
#pragma unroll
        for (int k = 0; k < 8; ++k) {
            int s = g.perm[i + k];
            u[k] = *reinterpret_cast<const unsigned*>(hb + (size_t)s * D + c);
        }
        float ax = 0.f, ay = 0.f;
#pragma unroll
        for (int k = 0; k < 8; ++k) { ax += bflo(u[k]); ay += bfhi(u[k]); }
        acc.x += ax;
        acc.y += ay;
    }
    if (i + 3 < end) {
        int s0 = g.perm[i], s1 = g.perm[i + 1];
        int s2 = g.perm[i + 2], s3 = g.perm[i + 3];
        unsigned u0 = *reinterpret_cast<const unsigned*>(hb + (size_t)s0 * D + c);
        unsigned u1 = *reinterpret_cast<const unsigned*>(hb + (size_t)s1 * D + c);
        unsigned u2 = *reinterpret_cast<const unsigned*>(hb + (size_t)s2 * D + c);
        unsigned u3 = *reinterpret_cast<const unsigned*>(hb + (size_t)s3 * D + c);
        acc.x += (bflo(u0) + bflo(u1)) + (bflo(u2) + bflo(u3));
        acc.y += (bfhi(u0) + bfhi(u1)) + (bfhi(u2) + bfhi(u3));
        i += 4;
    }
    for (; i < end; ++i) {
        unsigned u = *reinterpret_cast<const unsigned*>(hb + (size_t)g.perm[i] * D + c);
        acc.x += bflo(u);
        acc.y += bfhi(u);
    }
    unsigned o = (unsigned)f2bf(acc.x) | ((unsigned)f2bf(acc.y) << 16);
    *reinterpret_cast<unsigned*>(g.x + (size_t)row * D + c) = o;
}

// ---------------------------------------------------------------------------
__device__ __forceinline__ unsigned bnpack(unsigned u, float sLo, float sHi,
                                           float bLo, float bHi)
{
    float lo = fmaxf(fmaf(bflo(u), sLo, bLo), 0.f);
    float hi = fmaxf(fmaf(bfhi(u), sHi, bHi), 0.f);
    return (unsigned)f2bf(lo) | ((unsigned)f2bf(hi) << 16);
}

// ---------------------------------------------------------------------------
// Device-wide barrier over the FUSE_GX blocks of one relation. Safe because
// the fused grid (FUSE_GX x 2 = 512 blocks, 70.6KB LDS, <=256 VGPR via
// __launch_bounds__(256,2)) is exactly 2 blocks/CU x 256 CUs -> all blocks
// co-resident. Counter zeroed by prep each launch (graph-replay safe).
// ---------------------------------------------------------------------------
__device__ __forceinline__ void rel_barrier(int* ctr)
{
    __syncthreads();
    __threadfence();
    if (threadIdx.x == 0) {
        __hip_atomic_fetch_add(ctr, 1, __ATOMIC_ACQ_REL, __HIP_MEMORY_SCOPE_AGENT);
        while (__hip_atomic_load(ctr, __ATOMIC_ACQUIRE, __HIP_MEMORY_SCOPE_AGENT)
               < FUSE_GX)
            __builtin_amdgcn_s_sleep(1);
    }
    __syncthreads();
    __threadfence();
}

// ---------------------------------------------------------------------------
// Fused MLP: out = relu(bn2( relu(bn1(x@W1)) @ W2 )). One dispatch.
// 512 blocks (2/CU); block owns <=MAXT 64-row tiles; y/z live in LDS (bf16,
// XOR-swizzle byte^=(row&7)<<4 vs stride-256B bank conflicts). BN batch stats
// via device atomics + capacity barrier. Waves self-contained per 16-row strip.
// ---------------------------------------------------------------------------
__global__ __launch_bounds__(256, 2) void fused_mlp_kernel(FusedRel q0, FusedRel q1,
                                                           int* bar)
{
    FusedRel q = blockIdx.y ? q1 : q0;
    int* bA = bar + blockIdx.y * 2;
    __shared__ unsigned short ylds[MAXT * 64 * D];   // 64 KB
    __shared__ float s_sc[D], s_bi[D];
    __shared__ float ssum[4][D], ssq[4][D];
    char* yb = reinterpret_cast<char*>(ylds);

    const int t = threadIdx.x;
    const int w = t >> 6;
    const int l = t & 63;
    const int lr = l & 15;
    const int lk = (l >> 4) << 3;

    uint4 wf[4][8];
    float ps[8], pq[8];

    // ---------------- stage 1: y = x @ W1 -> LDS, stats1 ----------------
#pragma unroll
    for (int kk = 0; kk < 4; ++kk)
#pragma unroll
        for (int n = 0; n < 8; ++n)
            wf[kk][n] = *reinterpret_cast<const uint4*>(
                q.Wt1 + (size_t)(n * 16 + lr) * D + kk * 32 + lk);
#pragma unroll
    for (int n = 0; n < 8; ++n) { ps[n] = 0.f; pq[n] = 0.f; }

    for (int mt = 0; mt < MAXT; ++mt) {
        int tile = (int)blockIdx.x + mt * FUSE_GX;
        if (tile >= q.ntiles) break;
        f32x4 acc[8];
#pragma unroll
        for (int n = 0; n < 8; ++n) acc[n] = (f32x4){0.f, 0.f, 0.f, 0.f};
        const int arow = tile * 64 + w * 16 + lr;
#pragma unroll
        for (int kk = 0; kk < 4; ++kk) {
            uint4 a4 = make_uint4(0u, 0u, 0u, 0u);
            if (arow < q.N)
                a4 = *reinterpret_cast<const uint4*>(
                    q.X + (size_t)arow * D + kk * 32 + lk);
            short8 a = __builtin_bit_cast(short8, a4);
#pragma unroll
            for (int n = 0; n < 8; ++n)
                acc[n] = __builtin_amdgcn_mfma_f32_16x16x32_bf16(
                    a, __builtin_bit_cast(short8, wf[kk][n]), acc[n], 0, 0, 0);
        }
        const int lrow = w * 16 + ((l >> 4) << 2);
#pragma unroll
        for (int n = 0; n < 8; ++n) {
#pragma unroll
            for (int j = 0; j < 4; ++j) {
                float v = acc[n][j];
                ps[n] += v;           // pad rows are exact 0
                pq[n] += v * v;
                int row = lrow + j;
                int by = (((row << 8) + ((n * 16 + lr) << 1)) ^ ((row & 7) << 4));
                *reinterpret_cast<unsigned short*>(yb + mt * 16384 + by) = f2bf(v);
            }
        }
    }
#pragma unroll
    for (int n = 0; n < 8; ++n) {
        ps[n] += __shfl_xor(ps[n], 16); ps[n] += __shfl_xor(ps[n], 32);
        pq[n] += __shfl_xor(pq[n], 16); pq[n] += __shfl_xor(pq[n], 32);
    }
    if (l < 16) {
#pragma unroll
        for (int n = 0; n < 8; ++n) {
            ssum[w][n * 16 + l] = ps[n];
            ssq[w][n * 16 + l]  = pq[n];
        }
    }
    __syncthreads();
    if (t < D) {
        atomicAdd(&q.st[t], ssum[0][t] + ssum[1][t] + ssum[2][t] + ssum[3][t]);
        atomicAdd(&q.st[D + t], ssq[0][t] + ssq[1][t] + ssq[2][t] + ssq[3][t]);
    }
    rel_barrier(bA);

    // ---------------- stage 2: z = relu(bn1(y)) @ W2 -> LDS, stats2 -----
    if (t < D) {
        float inv_n = 1.f / (float)q.N;
        float mean = q.st[t] * inv_n;
        float var = fmaxf(q.st[D + t] * inv_n - mean * mean, 0.f);
        float s = q.g1[t] * rsqrtf(var + BN_EPS);
        s_sc[t] = s;
        s_bi[t] = q.b1[t] - mean * s;
    }
    __syncthreads();
#pragma unroll
    for (int kk = 0; kk < 4; ++kk)
#pragma unroll
        for (int n = 0; n < 8; ++n)
            wf[kk][n] = *reinterpret_cast<const uint4*>(
                q.Wt2 + (size_t)(n * 16 + lr) * D + kk * 32 + lk);
#pragma unroll
    for (int n = 0; n < 8; ++n) { ps[n] = 0.f; pq[n] = 0.f; }

    for (int mt = 0; mt < MAXT; ++mt) {
        int tile = (int)blockIdx.x + mt * FUSE_GX;
        if (tile >= q.ntiles) break;
        f32x4 acc[8];
#pragma unroll
        for (int n = 0; n < 8; ++n) acc[n] = (f32x4){0.f, 0.f, 0.f, 0.f};
        const int yrow = w * 16 + lr;
        const int grow = tile * 64 + yrow;
#pragma unroll
        for (int kk = 0; kk < 4; ++kk) {
            uint4 a4 = make_uint4(0u, 0u, 0u, 0u);
            if (grow < q.N) {
                int by = (((yrow << 8) + ((kk * 32 + lk) << 1)) ^ ((yrow & 7) << 4));
                a4 = *reinterpret_cast<const uint4*>(yb + mt * 16384 + by);
                const int kb = kk * 32 + lk;
                float4 s0 = *reinterpret_cast<const float4*>(&s_sc[kb]);
                float4 s1 = *reinterpret_cast<const float4*>(&s_sc[kb + 4]);
                float4 b0 = *reinterpret_cast<const float4*>(&s_bi[kb]);
                float4 b1 = *reinterpret_cast<const float4*>(&s_bi[kb + 4]);
                a4.x = bnpack(a4.x, s0.x, s0.y, b0.x, b0.y);
                a4.y = bnpack(a4.y, s0.z, s0.w, b0.z, b0.w);
                a4.z = bnpack(a4.z, s1.x, s1.y, b1.x, b1.y);
                a4.w = bnpack(a4.w, s1.z, s1.w, b1.z, b1.w);
            }
            short8 a = __builtin_bit_cast(short8, a4);
#pragma unroll
            for (int n = 0; n < 8; ++n)
                acc[n] = __builtin_amdgcn_mfma_f32_16x16x32_bf16(
                    a, __builtin_bit_cast(short8, wf[kk][n]), acc[n], 0, 0, 0);
        }
        __syncthreads();  // all waves done reading this tile's y before overwrite
        const int lrow = w * 16 + ((l >> 4) << 2);
#pragma unroll
        for (int n = 0; n < 8; ++n) {
#pragma unroll
            for (int j = 0; j < 4; ++j) {
                float v = acc[n][j];
                ps[n] += v;
                pq[n] += v * v;
                int row = lrow + j;
                int by = (((row << 8) + ((n * 16 + lr) << 1)) ^ ((row & 7) << 4));
                *reinterpret_cast<unsigned short*>(yb + mt * 16384 + by) = f2bf(v);
            }
        }
    }
#pragma unroll
    for (int n = 0; n < 8; ++n) {
        ps[n] += __shfl_xor(ps[n], 16); ps[n] += __shfl_xor(ps[n], 32);
        pq[n] += __shfl_xor(pq[n], 16); pq[n] += __shfl_xor(pq[n], 32);
    }
    __syncthreads();
    if (l < 16) {
#pragma unroll
        for (int n = 0; n < 8; ++n) {
            ssum[w][n * 16 + l] = ps[n];
            ssq[w][n * 16 + l]  = pq[n];
        }
    }
    __syncthreads();
    if (t < D) {
        atomicAdd(&q.st[2 * D + t], ssum[0][t] + ssum[1][t] + ssum[2][t] + ssum[3][t]);
        atomicAdd(&q.st[3 * D + t], ssq[0][t] + ssq[1][t] + ssq[2][t] + ssq[3][t]);
    }
    rel_barrier(bA + 1);

    // ---------------- stage 3: out = relu(bn2(z)) (f32) -----------------
    if (t < D) {
        float inv_n = 1.f / (float)q.N;
        float mean = q.st[2 * D + t] * inv_n;
        float var = fmaxf(q.st[3 * D + t] * inv_n - mean * mean, 0.f);
        float s = q.g2[t] * rsqrtf(var + BN_EPS);
        s_sc[t] = s;
        s_bi[t] = q.b2[t] - mean * s;
    }
    __syncthreads();
    const float sc0 = s_sc[2 * l], sc1 = s_sc[2 * l + 1];
    const float bi0 = s_bi[2 * l], bi1 = s_bi[2 * l + 1];
    for (int mt = 0; mt < MAXT; ++mt) {
        int tile = (int)blockIdx.x + mt * FUSE_GX;
        if (tile >= q.ntiles) break;
#pragma unroll
        for (int rr = 0; rr < 16; ++rr) {
            int row = w * 16 + rr;
            int grow = tile * 64 + row;
            if (grow >= q.N) break;
            int by = (((row << 8) + (l << 2)) ^ ((row & 7) << 4));
            unsigned u = *reinterpret_cast<const unsigned*>(yb + mt * 16384 + by);
            float2 o;
            o.x = fmaxf(fmaf(bflo(u), sc0, bi0), 0.f);
            o.y = fmaxf(fmaf(bfhi(u), sc1, bi1), 0.f);
            *reinterpret_cast<float2*>(q.out + (size_t)grow * D + 2 * l) = o;
        }
    }
}

// ---------------------------------------------------------------------------
extern "C" void kernel_launch(void* const* d_in, const int* in_sizes, int n_in,
                              void* d_out, int out_size, void* d_ws, size_t ws_size,
                              hipStream_t stream)
{
    const float* h_user   = (const float*)d_in[0];
    const float* h_item   = (const float*)d_in[1];
    const int* src_rates  = (const int*)d_in[2];
    const int* dst_rates  = (const int*)d_in[3];
    const int* src_rev    = (const int*)d_in[4];
    const int* dst_rev    = (const int*)d_in[5];
    const float* W1_rates = (const float*)d_in[6];
    const float* W2_rates = (const float*)d_in[7];
    const float* g1_rates = (const float*)d_in[8];
    const float* b1_rates = (const float*)d_in[9];
    const float* g2_rates = (const float*)d_in[10];
    const float* b2_rates = (const float*)d_in[11];
    const float* W1_rev   = (const float*)d_in[12];
    const float* W2_rev   = (const float*)d_in[13];
    const float* g1_rev   = (const float*)d_in[14];
    const float* b1_rev   = (const float*)d_in[15];
    const float* g2_rev   = (const float*)d_in[16];
    const float* b2_rev   = (const float*)d_in[17];

    const int n_user = in_sizes[0] / D;
    const int n_item = in_sizes[1] / D;
    const int E1 = in_sizes[2];
    const int E2 = in_sizes[4];

    const int bw4_0 = (n_item + 3) >> 2;
    const int bw4_1 = (n_user + 3) >> 2;

    char* p = (char*)d_ws;
    auto alloc = [&](size_t bytes) {
        char* q = p;
        p += (bytes + 255) & ~(size_t)255;
        return q;
    };
    unsigned short* hbu = (unsigned short*)alloc((size_t)n_user * D * 2);
    unsigned short* hbi = (unsigned short*)alloc((size_t)n_item * D * 2);
    unsigned short* xz0 = (unsigned short*)alloc((size_t)n_item * D * 2);
    unsigned short* xz1 = (unsigned short*)alloc((size_t)n_user * D * 2);
    unsigned short* wt  = (unsigned short*)alloc((size_t)4 * D * D * 2);
    float* stats   = (float*)alloc((size_t)8 * D * 4);
    int* bar       = (int*)alloc((size_t)8 * 4);
    int* counts0   = (int*)alloc((size_t)n_item * 4);
    int* counts1   = (int*)alloc((size_t)n_user * 4);
    int* offsets0  = (int*)alloc(((size_t)n_item + 1) * 4);
    int* offsets1  = (int*)alloc(((size_t)n_user + 1) * 4);
    int* bsum0     = (int*)alloc((size_t)64 * 4);
    int* bsum1     = (int*)alloc((size_t)64 * 4);
    int* perm0     = (int*)alloc((size_t)E1 * 4);
    int* perm1     = (int*)alloc((size_t)E2 * 4);
    unsigned char* rank0 = (unsigned char*)alloc((size_t)E1);
    unsigned char* rank1 = (unsigned char*)alloc((size_t)E2);
    unsigned* pc0  = (unsigned*)alloc((size_t)NCHF * bw4_0 * 4);
    unsigned* pc1  = (unsigned*)alloc((size_t)NCHF * bw4_1 * 4);

    float* out_user = (float*)d_out;
    float* out_item = out_user + (size_t)n_user * D;

    const int nu8 = n_user * D / 8, ni8 = n_item * D / 8;
    int pblocks = 65 + (nu8 + ni8 + 255) / 256;
    prep_kernel<<<pblocks, 256, 0, stream>>>(
        h_user, h_item, hbu, hbi, nu8, ni8,
        W1_rates, W2_rates, W1_rev, W2_rev, wt, stats, bar);

    float* st0 = stats;
    float* st1 = stats + 4 * D;

    CsrRel c0 = {src_rates, dst_rates, counts0, offsets0, bsum0, perm0,
                 rank0, pc0, E1, n_item, (n_item + 1023) / 1024};
    CsrRel c1 = {src_rev, dst_rev, counts1, offsets1, bsum1, perm1,
                 rank1, pc1, E2, n_user, (n_user + 1023) / 1024};

    int nmax = n_item > n_user ? n_item : n_user;
    int emax = E1 > E2 ? E1 : E2;
    int bw4m = bw4_0 > bw4_1 ? bw4_0 : bw4_1;
    int ns = c0.nscan > c1.nscan ? c0.nscan : c1.nscan;

    size_t hist_lds = (size_t)bw4m * 4;
    hist_kernel<<<dim3(NCHF, 2), 256, hist_lds, stream>>>(c0, c1);
    chunkpfx_kernel<<<dim3((bw4m + 255) / 256, 2), 256, 0, stream>>>(c0, c1);
    scan_offsets_kernel<<<dim3(ns, 2), 256, 0, stream>>>(c0, c1);
    int nfine = (emax + FILL_FINE - 1) / FILL_FINE;
    fill_kernel<<<dim3(NBUK * nfine, 2), 256, 0, stream>>>(c0, c1);

    GatherRel ga0 = {hbu, hbi, offsets0, perm0, xz0, n_item};
    GatherRel ga1 = {hbi, hbu, offsets1, perm1, xz1, n_user};
    int ab = (nmax + 3) / 4;
    gather_agg_kernel<<<dim3(ab, 2), 256, 0, stream>>>(ga0, ga1);

    // Fused MLP chain: one normal dispatch, capacity barrier inside.
    const int nt0 = (n_item + 63) / 64, nt1 = (n_user + 63) / 64;
    FusedRel f0 = {xz0, wt,             wt + (size_t)D * D,
                   g1_rates, b1_rates, g2_rates, b2_rates,
                   st0, out_item, n_item, nt0};
    FusedRel f1 = {xz1, wt + (size_t)2 * D * D, wt + (size_t)3 * D * D,
                   g1_rev, b1_rev, g2_rev, b2_rev,
                   st1, out_user, n_user, nt1};
    fused_mlp_kernel<<<dim3(FUSE_GX, 2), 256, 0, stream>>>(f0, f1, bar);
}

// Round 15
// 184.911 us; speedup vs baseline: 1.7787x; 1.7787x over previous
//
#include <hip/hip_runtime.h>

#define D 128
#define NBUK 4        // dst-range buckets for fill write locality
#define NCHF 128      // edge chunks per relation (hist/pc granularity)
#define FILL_FINE 1024
#define MAXT 4        // max row-tiles (64 rows) per block in fused MLP
#define FUSE_GX 256   // fused grid.x (x2 relations = 512 blocks = 2/CU exactly)
static constexpr float BN_EPS = 1e-5f;

typedef __attribute__((ext_vector_type(8))) short short8;
typedef __attribute__((ext_vector_type(4))) float f32x4;

// ---------------------------------------------------------------------------
// bf16 helpers (RNE)
// ---------------------------------------------------------------------------
__device__ __forceinline__ unsigned short f2bf(float f)
{
    unsigned u = __builtin_bit_cast(unsigned, f);
    unsigned r = u + 0x7fffu + ((u >> 16) & 1u);
    return (unsigned short)(r >> 16);
}
__device__ __forceinline__ float bflo(unsigned u)
{
    return __builtin_bit_cast(float, u << 16);
}
__device__ __forceinline__ float bfhi(unsigned u)
{
    return __builtin_bit_cast(float, u & 0xffff0000u);
}

// ---------------------------------------------------------------------------
// Param bundles (by value; blockIdx.y selects relation).
// ---------------------------------------------------------------------------
struct CsrRel {
    const int* src; const int* dst;
    int* counts; int* offsets; int* bsum; int* perm;
    unsigned char* rank8; unsigned* pc;
    int E; int N; int nscan;
};
struct GatherRel {
    const unsigned short* hb;
    const unsigned short* hbd;
    const int* offsets; const int* perm;
    unsigned short* x; int N;
};
struct FusedRel {
    const unsigned short* X;     // gathered x (bf16)
    const unsigned short* Wt1;   // W1^T bf16 [n][k]
    const unsigned short* Wt2;   // W2^T bf16
    const float* g1; const float* b1; const float* g2; const float* b2;
    float* st;                   // [sum1, sq1, sum2, sq2] x D (zeroed)
    float* out;                  // f32 output
    int N; int ntiles;
};

// ---------------------------------------------------------------------------
// Fused prep: blocks 0..63 weights; block 64 zeroes stats + barrier counters;
// blocks 65.. convert h tables to bf16.
// ---------------------------------------------------------------------------
__global__ __launch_bounds__(256) void prep_kernel(
    const float* __restrict__ hu, const float* __restrict__ hi,
    unsigned short* __restrict__ bu, unsigned short* __restrict__ bi8,
    int nu8, int ni8,
    const float* __restrict__ Wa, const float* __restrict__ Wb,
    const float* __restrict__ Wc, const float* __restrict__ Wd,
    unsigned short* __restrict__ wt, float* __restrict__ stats,
    int* __restrict__ bar)
{
    const int t = threadIdx.x;
    if (blockIdx.x < 64) {
        const int wsel = blockIdx.x >> 4;
        const float* W = wsel == 0 ? Wa : wsel == 1 ? Wb : wsel == 2 ? Wc : Wd;
        unsigned short* out = wt + (size_t)wsel * D * D;
        const int tile = blockIdx.x & 15;
        const int k0 = (tile >> 2) * 32, n0 = (tile & 3) * 32;
        __shared__ float s[32][33];
        const int r = t >> 3, c = (t & 7) * 4;
        float4 v = *reinterpret_cast<const float4*>(W + (size_t)(k0 + r) * D + n0 + c);
        s[r][c] = v.x; s[r][c + 1] = v.y; s[r][c + 2] = v.z; s[r][c + 3] = v.w;
        __syncthreads();
        unsigned lo = (unsigned)f2bf(s[c][r]) | ((unsigned)f2bf(s[c + 1][r]) << 16);
        unsigned hi = (unsigned)f2bf(s[c + 2][r]) | ((unsigned)f2bf(s[c + 3][r]) << 16);
        *reinterpret_cast<uint2*>(out + (size_t)(n0 + r) * D + k0 + c) =
            make_uint2(lo, hi);
        return;
    }
    if (blockIdx.x == 64) {
        reinterpret_cast<float4*>(stats)[t] = make_float4(0.f, 0.f, 0.f, 0.f);
        if (t < 8) bar[t] = 0;
        return;
    }
    int i = (blockIdx.x - 65) * 256 + t;
    if (i >= nu8 + ni8) return;
    const float* s; unsigned short* d; int o;
    if (i < nu8) { s = hu; d = bu; o = i; }
    else         { s = hi; d = bi8; o = i - nu8; }
    float4 v0 = reinterpret_cast<const float4*>(s)[o * 2];
    float4 v1 = reinterpret_cast<const float4*>(s)[o * 2 + 1];
    uint4 r;
    r.x = (unsigned)f2bf(v0.x) | ((unsigned)f2bf(v0.y) << 16);
    r.y = (unsigned)f2bf(v0.z) | ((unsigned)f2bf(v0.w) << 16);
    r.z = (unsigned)f2bf(v1.x) | ((unsigned)f2bf(v1.y) << 16);
    r.w = (unsigned)f2bf(v1.z) | ((unsigned)f2bf(v1.w) << 16);
    reinterpret_cast<uint4*>(d)[o] = r;
}

// ---------------------------------------------------------------------------
// CSR pass A: full-range u8x4-packed LDS histogram (dynamic LDS).
// ---------------------------------------------------------------------------
__global__ __launch_bounds__(256) void hist_kernel(CsrRel r0, CsrRel r1)
{
    CsrRel r = blockIdx.y ? r1 : r0;
    extern __shared__ unsigned h4[];
    const int t = threadIdx.x;
    const int c = blockIdx.x;
    const int CE = (r.E + NCHF - 1) / NCHF;
    const int e0 = c * CE;
    const int e1 = min(e0 + CE, r.E);
    const int bw4 = (r.N + 3) >> 2;

    for (int i = t; i < bw4; i += 256) h4[i] = 0u;
    __syncthreads();
    for (int e = e0 + t; e < e1; e += 256) {
        int d = r.dst[e];
        unsigned sh = (unsigned)(d & 3) * 8u;
        unsigned old = atomicAdd(&h4[d >> 2], 1u << sh);
        r.rank8[e] = (unsigned char)((old >> sh) & 0xffu);
    }
    __syncthreads();
    unsigned* out = r.pc + (size_t)c * bw4;
    for (int i = t; i < bw4; i += 256) out[i] = h4[i];
}

// ---------------------------------------------------------------------------
// CSR pass B: per-dst exclusive chunk-prefix (u8x4 lanes), totals -> counts,
// block partial -> bsum.
// ---------------------------------------------------------------------------
__global__ __launch_bounds__(256) void chunkpfx_kernel(CsrRel r0, CsrRel r1)
{
    CsrRel r = blockIdx.y ? r1 : r0;
    __shared__ unsigned lds[NCHF * 256];   // 128 KB
    const int t = threadIdx.x;
    const int j = blockIdx.x * 256 + t;
    const int bw4 = (r.N + 3) >> 2;
    int s = 0;
    if (j < bw4) {
        const unsigned* base = r.pc + j;
#pragma unroll 4
        for (int c = 0; c < NCHF; ++c)
            lds[c * 256 + t] = base[(size_t)c * bw4];
        unsigned s0 = 0, s1 = 0, s2 = 0, s3 = 0;
        for (int c = 0; c < NCHF; ++c) {
            unsigned v = lds[c * 256 + t];
            lds[c * 256 + t] = s0 | (s1 << 8) | (s2 << 16) | (s3 << 24);
            s0 += v & 0xffu;
            s1 += (v >> 8) & 0xffu;
            s2 += (v >> 16) & 0xffu;
            s3 += v >> 24;
        }
        unsigned* wb = r.pc + j;
#pragma unroll 4
        for (int c = 0; c < NCHF; ++c)
            wb[(size_t)c * bw4] = lds[c * 256 + t];
        int d0 = 4 * j;
        r.counts[d0] = (int)s0;
        if (d0 + 1 < r.N) r.counts[d0 + 1] = (int)s1;
        if (d0 + 2 < r.N) r.counts[d0 + 2] = (int)s2;
        if (d0 + 3 < r.N) r.counts[d0 + 3] = (int)s3;
        s = (int)(s0 + s1 + s2 + s3);
    }
    __shared__ int red[256];
    red[t] = s;
    __syncthreads();
    for (int off = 128; off > 0; off >>= 1) {
        if (t < off) red[t] += red[t + off];
        __syncthreads();
    }
    if (t == 0) r.bsum[blockIdx.x] = red[0];
}

// ---------------------------------------------------------------------------
// Offsets: inline <=64-entry partial scan + per-block 1024-dst scan.
// ---------------------------------------------------------------------------
__global__ __launch_bounds__(256) void scan_offsets_kernel(CsrRel rr0, CsrRel rr1)
{
    CsrRel r = blockIdx.y ? rr1 : rr0;
    if ((int)blockIdx.x >= r.nscan) return;
    __shared__ int pb[64];
    __shared__ int part[256];
    const int t = threadIdx.x;
    if (t == 0) {
        int run = 0;
        for (int i = 0; i < r.nscan; ++i) { pb[i] = run; run += r.bsum[i]; }
    }
    const int d0 = blockIdx.x * 1024 + t * 4;
    int v0 = 0, v1 = 0, v2 = 0, v3 = 0;
    if (d0 + 3 < r.N) {
        int4 q = *reinterpret_cast<const int4*>(r.counts + d0);
        v0 = q.x; v1 = q.y; v2 = q.z; v3 = q.w;
    } else {
        if (d0 < r.N) v0 = r.counts[d0];
        if (d0 + 1 < r.N) v1 = r.counts[d0 + 1];
        if (d0 + 2 < r.N) v2 = r.counts[d0 + 2];
        if (d0 + 3 < r.N) v3 = r.counts[d0 + 3];
    }
    int s = v0 + v1 + v2 + v3;
    part[t] = s;
    __syncthreads();
    for (int off = 1; off < 256; off <<= 1) {
        int tmp = (t >= off) ? part[t - off] : 0;
        __syncthreads();
        part[t] += tmp;
        __syncthreads();
    }
    int excl = part[t] - s + pb[blockIdx.x];
    int o0 = excl, o1 = o0 + v0, o2 = o1 + v1, o3 = o2 + v2;
    if (d0 + 3 < r.N) {
        *reinterpret_cast<int4*>(r.offsets + d0) = make_int4(o0, o1, o2, o3);
    } else {
        if (d0 < r.N) r.offsets[d0] = o0;
        if (d0 + 1 < r.N) r.offsets[d0 + 1] = o1;
        if (d0 + 2 < r.N) r.offsets[d0 + 2] = o2;
        if (d0 + 3 < r.N) r.offsets[d0 + 3] = o3;
    }
    if (d0 < r.N && d0 + 4 >= r.N) r.offsets[r.N] = excl + s;
}

// ---------------------------------------------------------------------------
// CSR pass C: perm fill, no atomics, NBUK dst buckets, fine blocks.
// ---------------------------------------------------------------------------
__global__ __launch_bounds__(256) void fill_kernel(CsrRel rr0, CsrRel rr1)
{
    CsrRel r = blockIdx.y ? rr1 : rr0;
    const int b = blockIdx.x & (NBUK - 1);
    const int fc = blockIdx.x >> 2;
    const int f0 = fc * FILL_FINE;
    if (f0 >= r.E) return;
    const int f1 = min(f0 + FILL_FINE, r.E);
    const int bw = (r.N + NBUK - 1) / NBUK;
    const int lo = b * bw;
    const int hi = min(lo + bw, r.N);
    const int CE = (r.E + NCHF - 1) / NCHF;
    const int c0 = f0 / CE;
    const int cb = (c0 + 1) * CE;
    const int bw4 = (r.N + 3) >> 2;
    const unsigned* pcb0 = r.pc + (size_t)c0 * bw4;
    const unsigned* pcb1 = pcb0 + bw4;
    for (int e = f0 + threadIdx.x; e < f1; e += 256) {
        int d = r.dst[e];
        if (d >= lo && d < hi) {
            const unsigned* pcc = (e >= cb) ? pcb1 : pcb0;
            unsigned sh = (unsigned)(d & 3) * 8u;
            int px = (int)((pcc[d >> 2] >> sh) & 0xffu);
            r.perm[r.offsets[d] + px + (int)r.rank8[e]] = r.src[e];
        }
    }
}

// ---------------------------------------------------------------------------
// Gather-aggregate, all-bf16 reads: x[row] = hbd[row] + sum hb[perm[i]].
// ---------------------------------------------------------------------------
__global__ __launch_bounds__(256) void gather_agg_kernel(GatherRel g0, GatherRel g1)
{
    GatherRel g = blockIdx.y ? g1 : g0;
    int row = blockIdx.x * 4 + (threadIdx.x >> 6);
    row = __builtin_amdgcn_readfirstlane(row);
    if (row >= g.N) return;
    const int c = (threadIdx.x & 63) * 2;
    const int beg = g.offsets[row], end = g.offsets[row + 1];
    unsigned us = *reinterpret_cast<const unsigned*>(g.hbd + (size_t)row * D + c);
    float2 acc = make_float2(bflo(us), bfhi(us));
    const unsigned short* hb = g.hb;
    int i = beg;
    for (; i + 7 < end; i += 8) {
        unsigned u[8];
#pragma unroll
        for (int k = 0; k < 8; ++k) {
            int s = g.perm[i + k];
            u[k] = *reinterpret_cast<const unsigned*>(hb + (size_t)s * D + c);
        }
        float ax = 0.f, ay = 0.f;
#pragma unroll
        for (int k = 0; k < 8; ++k) { ax += bflo(u[k]); ay += bfhi(u[k]); }
        acc.x += ax;
        acc.y += ay;
    }
    if (i + 3 < end) {
        int s0 = g.perm[i], s1 = g.perm[i + 1];
        int s2 = g.perm[i + 2], s3 = g.perm[i + 3];
        unsigned u0 = *reinterpret_cast<const unsigned*>(hb + (size_t)s0 * D + c);
        unsigned u1 = *reinterpret_cast<const unsigned*>(hb + (size_t)s1 * D + c);
        unsigned u2 = *reinterpret_cast<const unsigned*>(hb + (size_t)s2 * D + c);
        unsigned u3 = *reinterpret_cast<const unsigned*>(hb + (size_t)s3 * D + c);
        acc.x += (bflo(u0) + bflo(u1)) + (bflo(u2) + bflo(u3));
        acc.y += (bfhi(u0) + bfhi(u1)) + (bfhi(u2) + bfhi(u3));
        i += 4;
    }
    for (; i < end; ++i) {
        unsigned u = *reinterpret_cast<const unsigned*>(hb + (size_t)g.perm[i] * D + c);
        acc.x += bflo(u);
        acc.y += bfhi(u);
    }
    unsigned o = (unsigned)f2bf(acc.x) | ((unsigned)f2bf(acc.y) << 16);
    *reinterpret_cast<unsigned*>(g.x + (size_t)row * D + c) = o;
}

// ---------------------------------------------------------------------------
__device__ __forceinline__ unsigned bnpack(unsigned u, float sLo, float sHi,
                                           float bLo, float bHi)
{
    float lo = fmaxf(fmaf(bflo(u), sLo, bLo), 0.f);
    float hi = fmaxf(fmaf(bfhi(u), sHi, bHi), 0.f);
    return (unsigned)f2bf(lo) | ((unsigned)f2bf(hi) << 16);
}

// ---------------------------------------------------------------------------
// Fence-FREE capacity barrier. Correctness: (1) __syncthreads drains
// vmcnt(0), so the block's device-scope atomicAdds to st have completed at
// the coherence point before the counter bump; (2) post-barrier stats are
// read with agent-scope atomic loads (L1-bypassing), so no cache invalidate
// is needed; (3) one ACQUIRE load at exit orders the spin before those reads.
// r14's __threadfence (agent acq-rel = L2 writeback+inv per block) was the
// ~100us/barrier cost — removed.
// ---------------------------------------------------------------------------
__device__ __forceinline__ void rel_barrier(int* ctr)
{
    __syncthreads();
    if (threadIdx.x == 0) {
        __hip_atomic_fetch_add(ctr, 1, __ATOMIC_RELAXED, __HIP_MEMORY_SCOPE_AGENT);
        while (__hip_atomic_load(ctr, __ATOMIC_RELAXED, __HIP_MEMORY_SCOPE_AGENT)
               < FUSE_GX)
            __builtin_amdgcn_s_sleep(2);
        int v = __hip_atomic_load(ctr, __ATOMIC_ACQUIRE, __HIP_MEMORY_SCOPE_AGENT);
        asm volatile("" :: "s"(v));   // keep the acquire load live
    }
    __syncthreads();
}

__device__ __forceinline__ float ld_atomic(const float* p)
{
    return __hip_atomic_load(p, __ATOMIC_RELAXED, __HIP_MEMORY_SCOPE_AGENT);
}

// ---------------------------------------------------------------------------
// Fused MLP: out = relu(bn2( relu(bn1(x@W1)) @ W2 )). One dispatch.
// 512 blocks (2/CU); block owns <=MAXT 64-row tiles; y/z live in LDS (bf16,
// XOR-swizzle byte^=(row&7)<<4). BN batch stats via device atomics +
// fence-free capacity barrier. Waves self-contained per 16-row strip.
// ---------------------------------------------------------------------------
__global__ __launch_bounds__(256, 2) void fused_mlp_kernel(FusedRel q0, FusedRel q1,
                                                           int* bar)
{
    FusedRel q = blockIdx.y ? q1 : q0;
    int* bA = bar + blockIdx.y * 2;
    __shared__ unsigned short ylds[MAXT * 64 * D];   // 64 KB
    __shared__ float s_sc[D], s_bi[D];
    __shared__ float ssum[4][D], ssq[4][D];
    char* yb = reinterpret_cast<char*>(ylds);

    const int t = threadIdx.x;
    const int w = t >> 6;
    const int l = t & 63;
    const int lr = l & 15;
    const int lk = (l >> 4) << 3;

    uint4 wf[4][8];
    float ps[8], pq[8];

    // ---------------- stage 1: y = x @ W1 -> LDS, stats1 ----------------
#pragma unroll
    for (int kk = 0; kk < 4; ++kk)
#pragma unroll
        for (int n = 0; n < 8; ++n)
            wf[kk][n] = *reinterpret_cast<const uint4*>(
                q.Wt1 + (size_t)(n * 16 + lr) * D + kk * 32 + lk);
#pragma unroll
    for (int n = 0; n < 8; ++n) { ps[n] = 0.f; pq[n] = 0.f; }

    for (int mt = 0; mt < MAXT; ++mt) {
        int tile = (int)blockIdx.x + mt * FUSE_GX;
        if (tile >= q.ntiles) break;
        f32x4 acc[8];
#pragma unroll
        for (int n = 0; n < 8; ++n) acc[n] = (f32x4){0.f, 0.f, 0.f, 0.f};
        const int arow = tile * 64 + w * 16 + lr;
#pragma unroll
        for (int kk = 0; kk < 4; ++kk) {
            uint4 a4 = make_uint4(0u, 0u, 0u, 0u);
            if (arow < q.N)
                a4 = *reinterpret_cast<const uint4*>(
                    q.X + (size_t)arow * D + kk * 32 + lk);
            short8 a = __builtin_bit_cast(short8, a4);
#pragma unroll
            for (int n = 0; n < 8; ++n)
                acc[n] = __builtin_amdgcn_mfma_f32_16x16x32_bf16(
                    a, __builtin_bit_cast(short8, wf[kk][n]), acc[n], 0, 0, 0);
        }
        const int lrow = w * 16 + ((l >> 4) << 2);
#pragma unroll
        for (int n = 0; n < 8; ++n) {
#pragma unroll
            for (int j = 0; j < 4; ++j) {
                float v = acc[n][j];
                ps[n] += v;           // pad rows are exact 0
                pq[n] += v * v;
                int row = lrow + j;
                int by = (((row << 8) + ((n * 16 + lr) << 1)) ^ ((row & 7) << 4));
                *reinterpret_cast<unsigned short*>(yb + mt * 16384 + by) = f2bf(v);
            }
        }
    }
#pragma unroll
    for (int n = 0; n < 8; ++n) {
        ps[n] += __shfl_xor(ps[n], 16); ps[n] += __shfl_xor(ps[n], 32);
        pq[n] += __shfl_xor(pq[n], 16); pq[n] += __shfl_xor(pq[n], 32);
    }
    if (l < 16) {
#pragma unroll
        for (int n = 0; n < 8; ++n) {
            ssum[w][n * 16 + l] = ps[n];
            ssq[w][n * 16 + l]  = pq[n];
        }
    }
    __syncthreads();
    if (t < D) {
        atomicAdd(&q.st[t], ssum[0][t] + ssum[1][t] + ssum[2][t] + ssum[3][t]);
        atomicAdd(&q.st[D + t], ssq[0][t] + ssq[1][t] + ssq[2][t] + ssq[3][t]);
    }
    rel_barrier(bA);

    // ---------------- stage 2: z = relu(bn1(y)) @ W2 -> LDS, stats2 -----
    if (t < D) {
        float inv_n = 1.f / (float)q.N;
        float mean = ld_atomic(&q.st[t]) * inv_n;
        float var = fmaxf(ld_atomic(&q.st[D + t]) * inv_n - mean * mean, 0.f);
        float s = q.g1[t] * rsqrtf(var + BN_EPS);
        s_sc[t] = s;
        s_bi[t] = q.b1[t] - mean * s;
    }
    __syncthreads();
#pragma unroll
    for (int kk = 0; kk < 4; ++kk)
#pragma unroll
        for (int n = 0; n < 8; ++n)
            wf[kk][n] = *reinterpret_cast<const uint4*>(
                q.Wt2 + (size_t)(n * 16 + lr) * D + kk * 32 + lk);
#pragma unroll
    for (int n = 0; n < 8; ++n) { ps[n] = 0.f; pq[n] = 0.f; }

    for (int mt = 0; mt < MAXT; ++mt) {
        int tile = (int)blockIdx.x + mt * FUSE_GX;
        if (tile >= q.ntiles) break;
        f32x4 acc[8];
#pragma unroll
        for (int n = 0; n < 8; ++n) acc[n] = (f32x4){0.f, 0.f, 0.f, 0.f};
        const int yrow = w * 16 + lr;
        const int grow = tile * 64 + yrow;
#pragma unroll
        for (int kk = 0; kk < 4; ++kk) {
            uint4 a4 = make_uint4(0u, 0u, 0u, 0u);
            if (grow < q.N) {
                int by = (((yrow << 8) + ((kk * 32 + lk) << 1)) ^ ((yrow & 7) << 4));
                a4 = *reinterpret_cast<const uint4*>(yb + mt * 16384 + by);
                const int kb = kk * 32 + lk;
                float4 s0 = *reinterpret_cast<const float4*>(&s_sc[kb]);
                float4 s1 = *reinterpret_cast<const float4*>(&s_sc[kb + 4]);
                float4 b0 = *reinterpret_cast<const float4*>(&s_bi[kb]);
                float4 b1 = *reinterpret_cast<const float4*>(&s_bi[kb + 4]);
                a4.x = bnpack(a4.x, s0.x, s0.y, b0.x, b0.y);
                a4.y = bnpack(a4.y, s0.z, s0.w, b0.z, b0.w);
                a4.z = bnpack(a4.z, s1.x, s1.y, b1.x, b1.y);
                a4.w = bnpack(a4.w, s1.z, s1.w, b1.z, b1.w);
            }
            short8 a = __builtin_bit_cast(short8, a4);
#pragma unroll
            for (int n = 0; n < 8; ++n)
                acc[n] = __builtin_amdgcn_mfma_f32_16x16x32_bf16(
                    a, __builtin_bit_cast(short8, wf[kk][n]), acc[n], 0, 0, 0);
        }
        // Each wave reads/writes only its own 16-row strip -> no cross-wave
        // hazard; within-lane program order covers read-before-write.
        const int lrow = w * 16 + ((l >> 4) << 2);
#pragma unroll
        for (int n = 0; n < 8; ++n) {
#pragma unroll
            for (int j = 0; j < 4; ++j) {
                float v = acc[n][j];
                ps[n] += v;
                pq[n] += v * v;
                int row = lrow + j;
                int by = (((row << 8) + ((n * 16 + lr) << 1)) ^ ((row & 7) << 4));
                *reinterpret_cast<unsigned short*>(yb + mt * 16384 + by) = f2bf(v);
            }
        }
    }
#pragma unroll
    for (int n = 0; n < 8; ++n) {
        ps[n] += __shfl_xor(ps[n], 16); ps[n] += __shfl_xor(ps[n], 32);
        pq[n] += __shfl_xor(pq[n], 16); pq[n] += __shfl_xor(pq[n], 32);
    }
    __syncthreads();
    if (l < 16) {
#pragma unroll
        for (int n = 0; n < 8; ++n) {
            ssum[w][n * 16 + l] = ps[n];
            ssq[w][n * 16 + l]  = pq[n];
        }
    }
    __syncthreads();
    if (t < D) {
        atomicAdd(&q.st[2 * D + t], ssum[0][t] + ssum[1][t] + ssum[2][t] + ssum[3][t]);
        atomicAdd(&q.st[3 * D + t], ssq[0][t] + ssq[1][t] + ssq[2][t] + ssq[3][t]);
    }
    rel_barrier(bA + 1);

    // ---------------- stage 3: out = relu(bn2(z)) (f32) -----------------
    if (t < D) {
        float inv_n = 1.f / (float)q.N;
        float mean = ld_atomic(&q.st[2 * D + t]) * inv_n;
        float var = fmaxf(ld_atomic(&q.st[3 * D + t]) * inv_n - mean * mean, 0.f);
        float s = q.g2[t] * rsqrtf(var + BN_EPS);
        s_sc[t] = s;
        s_bi[t] = q.b2[t] - mean * s;
    }
    __syncthreads();
    const float sc0 = s_sc[2 * l], sc1 = s_sc[2 * l + 1];
    const float bi0 = s_bi[2 * l], bi1 = s_bi[2 * l + 1];
    for (int mt = 0; mt < MAXT; ++mt) {
        int tile = (int)blockIdx.x + mt * FUSE_GX;
        if (tile >= q.ntiles) break;
#pragma unroll
        for (int rr = 0; rr < 16; ++rr) {
            int row = w * 16 + rr;
            int grow = tile * 64 + row;
            if (grow >= q.N) break;
            int by = (((row << 8) + (l << 2)) ^ ((row & 7) << 4));
            unsigned u = *reinterpret_cast<const unsigned*>(yb + mt * 16384 + by);
            float2 o;
            o.x = fmaxf(fmaf(bflo(u), sc0, bi0), 0.f);
            o.y = fmaxf(fmaf(bfhi(u), sc1, bi1), 0.f);
            *reinterpret_cast<float2*>(q.out + (size_t)grow * D + 2 * l) = o;
        }
    }
}

// ---------------------------------------------------------------------------
extern "C" void kernel_launch(void* const* d_in, const int* in_sizes, int n_in,
                              void* d_out, int out_size, void* d_ws, size_t ws_size,
                              hipStream_t stream)
{
    const float* h_user   = (const float*)d_in[0];
    const float* h_item   = (const float*)d_in[1];
    const int* src_rates  = (const int*)d_in[2];
    const int* dst_rates  = (const int*)d_in[3];
    const int* src_rev    = (const int*)d_in[4];
    const int* dst_rev    = (const int*)d_in[5];
    const float* W1_rates = (const float*)d_in[6];
    const float* W2_rates = (const float*)d_in[7];
    const float* g1_rates = (const float*)d_in[8];
    const float* b1_rates = (const float*)d_in[9];
    const float* g2_rates = (const float*)d_in[10];
    const float* b2_rates = (const float*)d_in[11];
    const float* W1_rev   = (const float*)d_in[12];
    const float* W2_rev   = (const float*)d_in[13];
    const float* g1_rev   = (const float*)d_in[14];
    const float* b1_rev   = (const float*)d_in[15];
    const float* g2_rev   = (const float*)d_in[16];
    const float* b2_rev   = (const float*)d_in[17];

    const int n_user = in_sizes[0] / D;
    const int n_item = in_sizes[1] / D;
    const int E1 = in_sizes[2];
    const int E2 = in_sizes[4];

    const int bw4_0 = (n_item + 3) >> 2;
    const int bw4_1 = (n_user + 3) >> 2;

    char* p = (char*)d_ws;
    auto alloc = [&](size_t bytes) {
        char* q = p;
        p += (bytes + 255) & ~(size_t)255;
        return q;
    };
    unsigned short* hbu = (unsigned short*)alloc((size_t)n_user * D * 2);
    unsigned short* hbi = (unsigned short*)alloc((size_t)n_item * D * 2);
    unsigned short* xz0 = (unsigned short*)alloc((size_t)n_item * D * 2);
    unsigned short* xz1 = (unsigned short*)alloc((size_t)n_user * D * 2);
    unsigned short* wt  = (unsigned short*)alloc((size_t)4 * D * D * 2);
    float* stats   = (float*)alloc((size_t)8 * D * 4);
    int* bar       = (int*)alloc((size_t)8 * 4);
    int* counts0   = (int*)alloc((size_t)n_item * 4);
    int* counts1   = (int*)alloc((size_t)n_user * 4);
    int* offsets0  = (int*)alloc(((size_t)n_item + 1) * 4);
    int* offsets1  = (int*)alloc(((size_t)n_user + 1) * 4);
    int* bsum0     = (int*)alloc((size_t)64 * 4);
    int* bsum1     = (int*)alloc((size_t)64 * 4);
    int* perm0     = (int*)alloc((size_t)E1 * 4);
    int* perm1     = (int*)alloc((size_t)E2 * 4);
    unsigned char* rank0 = (unsigned char*)alloc((size_t)E1);
    unsigned char* rank1 = (unsigned char*)alloc((size_t)E2);
    unsigned* pc0  = (unsigned*)alloc((size_t)NCHF * bw4_0 * 4);
    unsigned* pc1  = (unsigned*)alloc((size_t)NCHF * bw4_1 * 4);

    float* out_user = (float*)d_out;
    float* out_item = out_user + (size_t)n_user * D;

    const int nu8 = n_user * D / 8, ni8 = n_item * D / 8;
    int pblocks = 65 + (nu8 + ni8 + 255) / 256;
    prep_kernel<<<pblocks, 256, 0, stream>>>(
        h_user, h_item, hbu, hbi, nu8, ni8,
        W1_rates, W2_rates, W1_rev, W2_rev, wt, stats, bar);

    float* st0 = stats;
    float* st1 = stats + 4 * D;

    CsrRel c0 = {src_rates, dst_rates, counts0, offsets0, bsum0, perm0,
                 rank0, pc0, E1, n_item, (n_item + 1023) / 1024};
    CsrRel c1 = {src_rev, dst_rev, counts1, offsets1, bsum1, perm1,
                 rank1, pc1, E2, n_user, (n_user + 1023) / 1024};

    int nmax = n_item > n_user ? n_item : n_user;
    int emax = E1 > E2 ? E1 : E2;
    int bw4m = bw4_0 > bw4_1 ? bw4_0 : bw4_1;
    int ns = c0.nscan > c1.nscan ? c0.nscan : c1.nscan;

    size_t hist_lds = (size_t)bw4m * 4;
    hist_kernel<<<dim3(NCHF, 2), 256, hist_lds, stream>>>(c0, c1);
    chunkpfx_kernel<<<dim3((bw4m + 255) / 256, 2), 256, 0, stream>>>(c0, c1);
    scan_offsets_kernel<<<dim3(ns, 2), 256, 0, stream>>>(c0, c1);
    int nfine = (emax + FILL_FINE - 1) / FILL_FINE;
    fill_kernel<<<dim3(NBUK * nfine, 2), 256, 0, stream>>>(c0, c1);

    GatherRel ga0 = {hbu, hbi, offsets0, perm0, xz0, n_item};
    GatherRel ga1 = {hbi, hbu, offsets1, perm1, xz1, n_user};
    int ab = (nmax + 3) / 4;
    gather_agg_kernel<<<dim3(ab, 2), 256, 0, stream>>>(ga0, ga1);

    // Fused MLP chain: one normal dispatch, fence-free capacity barrier.
    const int nt0 = (n_item + 63) / 64, nt1 = (n_user + 63) / 64;
    FusedRel f0 = {xz0, wt,             wt + (size_t)D * D,
                   g1_rates, b1_rates, g2_rates, b2_rates,
                   st0, out_item, n_item, nt0};
    FusedRel f1 = {xz1, wt + (size_t)2 * D * D, wt + (size_t)3 * D * D,
                   g1_rev, b1_rev, g2_rev, b2_rev,
                   st1, out_user, n_user, nt1};
    fused_mlp_kernel<<<dim3(FUSE_GX, 2), 256, 0, stream>>>(f0, f1, bar);
}

// Round 16
// 184.512 us; speedup vs baseline: 1.7826x; 1.0022x over previous
//
#include <hip/hip_runtime.h>

#define D 128
#define NBUK 4        // dst-range buckets for fill write locality
#define NCHF 128      // edge chunks per relation (hist/pc granularity)
#define FILL_FINE 1024
#define MAXT 4        // max row-tiles (64 rows) per block in fused MLP
#define FUSE_GX 256   // fused grid.x (x2 relations = 512 blocks = 2/CU exactly)
static constexpr float BN_EPS = 1e-5f;

typedef __attribute__((ext_vector_type(8))) short short8;
typedef __attribute__((ext_vector_type(4))) float f32x4;

// ---------------------------------------------------------------------------
// bf16 helpers (RNE)
// ---------------------------------------------------------------------------
__device__ __forceinline__ unsigned short f2bf(float f)
{
    unsigned u = __builtin_bit_cast(unsigned, f);
    unsigned r = u + 0x7fffu + ((u >> 16) & 1u);
    return (unsigned short)(r >> 16);
}
__device__ __forceinline__ float bflo(unsigned u)
{
    return __builtin_bit_cast(float, u << 16);
}
__device__ __forceinline__ float bfhi(unsigned u)
{
    return __builtin_bit_cast(float, u & 0xffff0000u);
}

// ---------------------------------------------------------------------------
// Param bundles (by value; blockIdx.y selects relation).
// ---------------------------------------------------------------------------
struct CsrRel {
    const int* src; const int* dst;
    int* counts; int* offsets; int* bsum; int* perm;
    unsigned char* rank8; unsigned* pc;
    int E; int N; int nscan;
};
struct GatherRel {
    const unsigned short* hb;
    const unsigned short* hbd;
    const int* offsets; const int* perm;
    unsigned short* x; int N;
};
struct FusedRel {
    const unsigned short* X;     // gathered x (bf16)
    const unsigned short* Wt1;   // W1^T bf16 [n][k]
    const unsigned short* Wt2;   // W2^T bf16
    const float* g1; const float* b1; const float* g2; const float* b2;
    float* st;                   // [sum1, sq1, sum2, sq2] x D (zeroed)
    float* out;                  // f32 output
    int N; int ntiles;
};

// ---------------------------------------------------------------------------
// Fused prep: blocks 0..63 weights; block 64 zeroes stats + barrier counters;
// blocks 65.. convert h tables to bf16.
// ---------------------------------------------------------------------------
__global__ __launch_bounds__(256) void prep_kernel(
    const float* __restrict__ hu, const float* __restrict__ hi,
    unsigned short* __restrict__ bu, unsigned short* __restrict__ bi8,
    int nu8, int ni8,
    const float* __restrict__ Wa, const float* __restrict__ Wb,
    const float* __restrict__ Wc, const float* __restrict__ Wd,
    unsigned short* __restrict__ wt, float* __restrict__ stats,
    int* __restrict__ bar)
{
    const int t = threadIdx.x;
    if (blockIdx.x < 64) {
        const int wsel = blockIdx.x >> 4;
        const float* W = wsel == 0 ? Wa : wsel == 1 ? Wb : wsel == 2 ? Wc : Wd;
        unsigned short* out = wt + (size_t)wsel * D * D;
        const int tile = blockIdx.x & 15;
        const int k0 = (tile >> 2) * 32, n0 = (tile & 3) * 32;
        __shared__ float s[32][33];
        const int r = t >> 3, c = (t & 7) * 4;
        float4 v = *reinterpret_cast<const float4*>(W + (size_t)(k0 + r) * D + n0 + c);
        s[r][c] = v.x; s[r][c + 1] = v.y; s[r][c + 2] = v.z; s[r][c + 3] = v.w;
        __syncthreads();
        unsigned lo = (unsigned)f2bf(s[c][r]) | ((unsigned)f2bf(s[c + 1][r]) << 16);
        unsigned hi = (unsigned)f2bf(s[c + 2][r]) | ((unsigned)f2bf(s[c + 3][r]) << 16);
        *reinterpret_cast<uint2*>(out + (size_t)(n0 + r) * D + k0 + c) =
            make_uint2(lo, hi);
        return;
    }
    if (blockIdx.x == 64) {
        reinterpret_cast<float4*>(stats)[t] = make_float4(0.f, 0.f, 0.f, 0.f);
        if (t < 8) bar[t] = 0;
        return;
    }
    int i = (blockIdx.x - 65) * 256 + t;
    if (i >= nu8 + ni8) return;
    const float* s; unsigned short* d; int o;
    if (i < nu8) { s = hu; d = bu; o = i; }
    else         { s = hi; d = bi8; o = i - nu8; }
    float4 v0 = reinterpret_cast<const float4*>(s)[o * 2];
    float4 v1 = reinterpret_cast<const float4*>(s)[o * 2 + 1];
    uint4 r;
    r.x = (unsigned)f2bf(v0.x) | ((unsigned)f2bf(v0.y) << 16);
    r.y = (unsigned)f2bf(v0.z) | ((unsigned)f2bf(v0.w) << 16);
    r.z = (unsigned)f2bf(v1.x) | ((unsigned)f2bf(v1.y) << 16);
    r.w = (unsigned)f2bf(v1.z) | ((unsigned)f2bf(v1.w) << 16);
    reinterpret_cast<uint4*>(d)[o] = r;
}

// ---------------------------------------------------------------------------
// CSR pass A: full-range u8x4-packed LDS histogram (dynamic LDS).
// ---------------------------------------------------------------------------
__global__ __launch_bounds__(256) void hist_kernel(CsrRel r0, CsrRel r1)
{
    CsrRel r = blockIdx.y ? r1 : r0;
    extern __shared__ unsigned h4[];
    const int t = threadIdx.x;
    const int c = blockIdx.x;
    const int CE = (r.E + NCHF - 1) / NCHF;
    const int e0 = c * CE;
    const int e1 = min(e0 + CE, r.E);
    const int bw4 = (r.N + 3) >> 2;

    for (int i = t; i < bw4; i += 256) h4[i] = 0u;
    __syncthreads();
    for (int e = e0 + t; e < e1; e += 256) {
        int d = r.dst[e];
        unsigned sh = (unsigned)(d & 3) * 8u;
        unsigned old = atomicAdd(&h4[d >> 2], 1u << sh);
        r.rank8[e] = (unsigned char)((old >> sh) & 0xffu);
    }
    __syncthreads();
    unsigned* out = r.pc + (size_t)c * bw4;
    for (int i = t; i < bw4; i += 256) out[i] = h4[i];
}

// ---------------------------------------------------------------------------
// CSR pass B: per-dst exclusive chunk-prefix (u8x4 lanes), totals -> counts,
// block partial -> bsum.
// ---------------------------------------------------------------------------
__global__ __launch_bounds__(256) void chunkpfx_kernel(CsrRel r0, CsrRel r1)
{
    CsrRel r = blockIdx.y ? r1 : r0;
    __shared__ unsigned lds[NCHF * 256];   // 128 KB
    const int t = threadIdx.x;
    const int j = blockIdx.x * 256 + t;
    const int bw4 = (r.N + 3) >> 2;
    int s = 0;
    if (j < bw4) {
        const unsigned* base = r.pc + j;
#pragma unroll 4
        for (int c = 0; c < NCHF; ++c)
            lds[c * 256 + t] = base[(size_t)c * bw4];
        unsigned s0 = 0, s1 = 0, s2 = 0, s3 = 0;
        for (int c = 0; c < NCHF; ++c) {
            unsigned v = lds[c * 256 + t];
            lds[c * 256 + t] = s0 | (s1 << 8) | (s2 << 16) | (s3 << 24);
            s0 += v & 0xffu;
            s1 += (v >> 8) & 0xffu;
            s2 += (v >> 16) & 0xffu;
            s3 += v >> 24;
        }
        unsigned* wb = r.pc + j;
#pragma unroll 4
        for (int c = 0; c < NCHF; ++c)
            wb[(size_t)c * bw4] = lds[c * 256 + t];
        int d0 = 4 * j;
        r.counts[d0] = (int)s0;
        if (d0 + 1 < r.N) r.counts[d0 + 1] = (int)s1;
        if (d0 + 2 < r.N) r.counts[d0 + 2] = (int)s2;
        if (d0 + 3 < r.N) r.counts[d0 + 3] = (int)s3;
        s = (int)(s0 + s1 + s2 + s3);
    }
    __shared__ int red[256];
    red[t] = s;
    __syncthreads();
    for (int off = 128; off > 0; off >>= 1) {
        if (t < off) red[t] += red[t + off];
        __syncthreads();
    }
    if (t == 0) r.bsum[blockIdx.x] = red[0];
}

// ---------------------------------------------------------------------------
// Offsets: inline <=64-entry partial scan + per-block 1024-dst scan.
// ---------------------------------------------------------------------------
__global__ __launch_bounds__(256) void scan_offsets_kernel(CsrRel rr0, CsrRel rr1)
{
    CsrRel r = blockIdx.y ? rr1 : rr0;
    if ((int)blockIdx.x >= r.nscan) return;
    __shared__ int pb[64];
    __shared__ int part[256];
    const int t = threadIdx.x;
    if (t == 0) {
        int run = 0;
        for (int i = 0; i < r.nscan; ++i) { pb[i] = run; run += r.bsum[i]; }
    }
    const int d0 = blockIdx.x * 1024 + t * 4;
    int v0 = 0, v1 = 0, v2 = 0, v3 = 0;
    if (d0 + 3 < r.N) {
        int4 q = *reinterpret_cast<const int4*>(r.counts + d0);
        v0 = q.x; v1 = q.y; v2 = q.z; v3 = q.w;
    } else {
        if (d0 < r.N) v0 = r.counts[d0];
        if (d0 + 1 < r.N) v1 = r.counts[d0 + 1];
        if (d0 + 2 < r.N) v2 = r.counts[d0 + 2];
        if (d0 + 3 < r.N) v3 = r.counts[d0 + 3];
    }
    int s = v0 + v1 + v2 + v3;
    part[t] = s;
    __syncthreads();
    for (int off = 1; off < 256; off <<= 1) {
        int tmp = (t >= off) ? part[t - off] : 0;
        __syncthreads();
        part[t] += tmp;
        __syncthreads();
    }
    int excl = part[t] - s + pb[blockIdx.x];
    int o0 = excl, o1 = o0 + v0, o2 = o1 + v1, o3 = o2 + v2;
    if (d0 + 3 < r.N) {
        *reinterpret_cast<int4*>(r.offsets + d0) = make_int4(o0, o1, o2, o3);
    } else {
        if (d0 < r.N) r.offsets[d0] = o0;
        if (d0 + 1 < r.N) r.offsets[d0 + 1] = o1;
        if (d0 + 2 < r.N) r.offsets[d0 + 2] = o2;
        if (d0 + 3 < r.N) r.offsets[d0 + 3] = o3;
    }
    if (d0 < r.N && d0 + 4 >= r.N) r.offsets[r.N] = excl + s;
}

// ---------------------------------------------------------------------------
// CSR pass C: perm fill, no atomics, NBUK dst buckets, fine blocks.
// ---------------------------------------------------------------------------
__global__ __launch_bounds__(256) void fill_kernel(CsrRel rr0, CsrRel rr1)
{
    CsrRel r = blockIdx.y ? rr1 : rr0;
    const int b = blockIdx.x & (NBUK - 1);
    const int fc = blockIdx.x >> 2;
    const int f0 = fc * FILL_FINE;
    if (f0 >= r.E) return;
    const int f1 = min(f0 + FILL_FINE, r.E);
    const int bw = (r.N + NBUK - 1) / NBUK;
    const int lo = b * bw;
    const int hi = min(lo + bw, r.N);
    const int CE = (r.E + NCHF - 1) / NCHF;
    const int c0 = f0 / CE;
    const int cb = (c0 + 1) * CE;
    const int bw4 = (r.N + 3) >> 2;
    const unsigned* pcb0 = r.pc + (size_t)c0 * bw4;
    const unsigned* pcb1 = pcb0 + bw4;
    for (int e = f0 + threadIdx.x; e < f1; e += 256) {
        int d = r.dst[e];
        if (d >= lo && d < hi) {
            const unsigned* pcc = (e >= cb) ? pcb1 : pcb0;
            unsigned sh = (unsigned)(d & 3) * 8u;
            int px = (int)((pcc[d >> 2] >> sh) & 0xffu);
            r.perm[r.offsets[d] + px + (int)r.rank8[e]] = r.src[e];
        }
    }
}

// ---------------------------------------------------------------------------
// Gather-aggregate, all-bf16 reads: x[row] = hbd[row] + sum hb[perm[i]].
// ---------------------------------------------------------------------------
__global__ __launch_bounds__(256) void gather_agg_kernel(GatherRel g0, GatherRel g1)
{
    GatherRel g = blockIdx.y ? g1 : g0;
    int row = blockIdx.x * 4 + (threadIdx.x >> 6);
    row = __builtin_amdgcn_readfirstlane(row);
    if (row >= g.N) return;
    const int c = (threadIdx.x & 63) * 2;
    const int beg = g.offsets[row], end = g.offsets[row + 1];
    unsigned us = *reinterpret_cast<const unsigned*>(g.hbd + (size_t)row * D + c);
    float2 acc = make_float2(bflo(us), bfhi(us));
    const unsigned short* hb = g.hb;
    int i = beg;
    for (; i + 7 < end; i += 8) {
        unsigned u[8];
#pragma unroll
        for (int k = 0; k < 8; ++k) {
            int s = g.perm[i + k];
            u[k] = *reinterpret_cast<const unsigned*>(hb + (size_t)s * D + c);
        }
        float ax = 0.f, ay = 0.f;
#pragma unroll
        for (int k = 0; k < 8; ++k) { ax += bflo(u[k]); ay += bfhi(u[k]); }
        acc.x += ax;
        acc.y += ay;
    }
    if (i + 3 < end) {
        int s0 = g.perm[i], s1 = g.perm[i + 1];
        int s2 = g.perm[i + 2], s3 = g.perm[i + 3];
        unsigned u0 = *reinterpret_cast<const unsigned*>(hb + (size_t)s0 * D + c);
        unsigned u1 = *reinterpret_cast<const unsigned*>(hb + (size_t)s1 * D + c);
        unsigned u2 = *reinterpret_cast<const unsigned*>(hb + (size_t)s2 * D + c);
        unsigned u3 = *reinterpret_cast<const unsigned*>(hb + (size_t)s3 * D + c);
        acc.x += (bflo(u0) + bflo(u1)) + (bflo(u2) + bflo(u3));
        acc.y += (bfhi(u0) + bfhi(u1)) + (bfhi(u2) + bfhi(u3));
        i += 4;
    }
    for (; i < end; ++i) {
        unsigned u = *reinterpret_cast<const unsigned*>(hb + (size_t)g.perm[i] * D + c);
        acc.x += bflo(u);
        acc.y += bfhi(u);
    }
    unsigned o = (unsigned)f2bf(acc.x) | ((unsigned)f2bf(acc.y) << 16);
    *reinterpret_cast<unsigned*>(g.x + (size_t)row * D + c) = o;
}

// ---------------------------------------------------------------------------
__device__ __forceinline__ unsigned bnpack(unsigned u, float sLo, float sHi,
                                           float bLo, float bHi)
{
    float lo = fmaxf(fmaf(bflo(u), sLo, bLo), 0.f);
    float hi = fmaxf(fmaf(bfhi(u), sHi, bHi), 0.f);
    return (unsigned)f2bf(lo) | ((unsigned)f2bf(hi) << 16);
}

// ---------------------------------------------------------------------------
// Fence-FREE capacity barrier. Correctness: (1) __syncthreads drains
// vmcnt(0), so the block's device-scope atomicAdds to st have completed at
// the coherence point before the counter bump; (2) post-barrier stats are
// read with agent-scope atomic loads (L1-bypassing), so no cache invalidate
// is needed; (3) one ACQUIRE load at exit orders the spin before those reads.
// r14's __threadfence (agent acq-rel = L2 writeback+inv per block) was the
// ~100us/barrier cost — removed.
// ---------------------------------------------------------------------------
__device__ __forceinline__ void rel_barrier(int* ctr)
{
    __syncthreads();
    if (threadIdx.x == 0) {
        __hip_atomic_fetch_add(ctr, 1, __ATOMIC_RELAXED, __HIP_MEMORY_SCOPE_AGENT);
        while (__hip_atomic_load(ctr, __ATOMIC_RELAXED, __HIP_MEMORY_SCOPE_AGENT)
               < FUSE_GX)
            __builtin_amdgcn_s_sleep(2);
        int v = __hip_atomic_load(ctr, __ATOMIC_ACQUIRE, __HIP_MEMORY_SCOPE_AGENT);
        asm volatile("" :: "s"(v));   // keep the acquire load live
    }
    __syncthreads();
}

__device__ __forceinline__ float ld_atomic(const float* p)
{
    return __hip_atomic_load(p, __ATOMIC_RELAXED, __HIP_MEMORY_SCOPE_AGENT);
}

// ---------------------------------------------------------------------------
// Fused MLP: out = relu(bn2( relu(bn1(x@W1)) @ W2 )). One dispatch.
// 512 blocks (2/CU); block owns <=MAXT 64-row tiles; y/z live in LDS (bf16,
// XOR-swizzle byte^=(row&7)<<4). BN batch stats via device atomics +
// fence-free capacity barrier. Waves self-contained per 16-row strip.
// ---------------------------------------------------------------------------
__global__ __launch_bounds__(256, 2) void fused_mlp_kernel(FusedRel q0, FusedRel q1,
                                                           int* bar)
{
    FusedRel q = blockIdx.y ? q1 : q0;
    int* bA = bar + blockIdx.y * 2;
    __shared__ unsigned short ylds[MAXT * 64 * D];   // 64 KB
    __shared__ float s_sc[D], s_bi[D];
    __shared__ float ssum[4][D], ssq[4][D];
    char* yb = reinterpret_cast<char*>(ylds);

    const int t = threadIdx.x;
    const int w = t >> 6;
    const int l = t & 63;
    const int lr = l & 15;
    const int lk = (l >> 4) << 3;

    uint4 wf[4][8];
    float ps[8], pq[8];

    // ---------------- stage 1: y = x @ W1 -> LDS, stats1 ----------------
#pragma unroll
    for (int kk = 0; kk < 4; ++kk)
#pragma unroll
        for (int n = 0; n < 8; ++n)
            wf[kk][n] = *reinterpret_cast<const uint4*>(
                q.Wt1 + (size_t)(n * 16 + lr) * D + kk * 32 + lk);
#pragma unroll
    for (int n = 0; n < 8; ++n) { ps[n] = 0.f; pq[n] = 0.f; }

    for (int mt = 0; mt < MAXT; ++mt) {
        int tile = (int)blockIdx.x + mt * FUSE_GX;
        if (tile >= q.ntiles) break;
        f32x4 acc[8];
#pragma unroll
        for (int n = 0; n < 8; ++n) acc[n] = (f32x4){0.f, 0.f, 0.f, 0.f};
        const int arow = tile * 64 + w * 16 + lr;
#pragma unroll
        for (int kk = 0; kk < 4; ++kk) {
            uint4 a4 = make_uint4(0u, 0u, 0u, 0u);
            if (arow < q.N)
                a4 = *reinterpret_cast<const uint4*>(
                    q.X + (size_t)arow * D + kk * 32 + lk);
            short8 a = __builtin_bit_cast(short8, a4);
#pragma unroll
            for (int n = 0; n < 8; ++n)
                acc[n] = __builtin_amdgcn_mfma_f32_16x16x32_bf16(
                    a, __builtin_bit_cast(short8, wf[kk][n]), acc[n], 0, 0, 0);
        }
        const int lrow = w * 16 + ((l >> 4) << 2);
#pragma unroll
        for (int n = 0; n < 8; ++n) {
#pragma unroll
            for (int j = 0; j < 4; ++j) {
                float v = acc[n][j];
                ps[n] += v;           // pad rows are exact 0
                pq[n] += v * v;
                int row = lrow + j;
                int by = (((row << 8) + ((n * 16 + lr) << 1)) ^ ((row & 7) << 4));
                *reinterpret_cast<unsigned short*>(yb + mt * 16384 + by) = f2bf(v);
            }
        }
    }
#pragma unroll
    for (int n = 0; n < 8; ++n) {
        ps[n] += __shfl_xor(ps[n], 16); ps[n] += __shfl_xor(ps[n], 32);
        pq[n] += __shfl_xor(pq[n], 16); pq[n] += __shfl_xor(pq[n], 32);
    }
    if (l < 16) {
#pragma unroll
        for (int n = 0; n < 8; ++n) {
            ssum[w][n * 16 + l] = ps[n];
            ssq[w][n * 16 + l]  = pq[n];
        }
    }
    __syncthreads();
    if (t < D) {
        atomicAdd(&q.st[t], ssum[0][t] + ssum[1][t] + ssum[2][t] + ssum[3][t]);
        atomicAdd(&q.st[D + t], ssq[0][t] + ssq[1][t] + ssq[2][t] + ssq[3][t]);
    }
    rel_barrier(bA);

    // ---------------- stage 2: z = relu(bn1(y)) @ W2 -> LDS, stats2 -----
    if (t < D) {
        float inv_n = 1.f / (float)q.N;
        float mean = ld_atomic(&q.st[t]) * inv_n;
        float var = fmaxf(ld_atomic(&q.st[D + t]) * inv_n - mean * mean, 0.f);
        float s = q.g1[t] * rsqrtf(var + BN_EPS);
        s_sc[t] = s;
        s_bi[t] = q.b1[t] - mean * s;
    }
    __syncthreads();
#pragma unroll
    for (int kk = 0; kk < 4; ++kk)
#pragma unroll
        for (int n = 0; n < 8; ++n)
            wf[kk][n] = *reinterpret_cast<const uint4*>(
                q.Wt2 + (size_t)(n * 16 + lr) * D + kk * 32 + lk);
#pragma unroll
    for (int n = 0; n < 8; ++n) { ps[n] = 0.f; pq[n] = 0.f; }

    for (int mt = 0; mt < MAXT; ++mt) {
        int tile = (int)blockIdx.x + mt * FUSE_GX;
        if (tile >= q.ntiles) break;
        f32x4 acc[8];
#pragma unroll
        for (int n = 0; n < 8; ++n) acc[n] = (f32x4){0.f, 0.f, 0.f, 0.f};
        const int yrow = w * 16 + lr;
        const int grow = tile * 64 + yrow;
#pragma unroll
        for (int kk = 0; kk < 4; ++kk) {
            uint4 a4 = make_uint4(0u, 0u, 0u, 0u);
            if (grow < q.N) {
                int by = (((yrow << 8) + ((kk * 32 + lk) << 1)) ^ ((yrow & 7) << 4));
                a4 = *reinterpret_cast<const uint4*>(yb + mt * 16384 + by);
                const int kb = kk * 32 + lk;
                float4 s0 = *reinterpret_cast<const float4*>(&s_sc[kb]);
                float4 s1 = *reinterpret_cast<const float4*>(&s_sc[kb + 4]);
                float4 b0 = *reinterpret_cast<const float4*>(&s_bi[kb]);
                float4 b1 = *reinterpret_cast<const float4*>(&s_bi[kb + 4]);
                a4.x = bnpack(a4.x, s0.x, s0.y, b0.x, b0.y);
                a4.y = bnpack(a4.y, s0.z, s0.w, b0.z, b0.w);
                a4.z = bnpack(a4.z, s1.x, s1.y, b1.x, b1.y);
                a4.w = bnpack(a4.w, s1.z, s1.w, b1.z, b1.w);
            }
            short8 a = __builtin_bit_cast(short8, a4);
#pragma unroll
            for (int n = 0; n < 8; ++n)
                acc[n] = __builtin_amdgcn_mfma_f32_16x16x32_bf16(
                    a, __builtin_bit_cast(short8, wf[kk][n]), acc[n], 0, 0, 0);
        }
        // Each wave reads/writes only its own 16-row strip -> no cross-wave
        // hazard; within-lane program order covers read-before-write.
        const int lrow = w * 16 + ((l >> 4) << 2);
#pragma unroll
        for (int n = 0; n < 8; ++n) {
#pragma unroll
            for (int j = 0; j < 4; ++j) {
                float v = acc[n][j];
                ps[n] += v;
                pq[n] += v * v;
                int row = lrow + j;
                int by = (((row << 8) + ((n * 16 + lr) << 1)) ^ ((row & 7) << 4));
                *reinterpret_cast<unsigned short*>(yb + mt * 16384 + by) = f2bf(v);
            }
        }
    }
#pragma unroll
    for (int n = 0; n < 8; ++n) {
        ps[n] += __shfl_xor(ps[n], 16); ps[n] += __shfl_xor(ps[n], 32);
        pq[n] += __shfl_xor(pq[n], 16); pq[n] += __shfl_xor(pq[n], 32);
    }
    __syncthreads();
    if (l < 16) {
#pragma unroll
        for (int n = 0; n < 8; ++n) {
            ssum[w][n * 16 + l] = ps[n];
            ssq[w][n * 16 + l]  = pq[n];
        }
    }
    __syncthreads();
    if (t < D) {
        atomicAdd(&q.st[2 * D + t], ssum[0][t] + ssum[1][t] + ssum[2][t] + ssum[3][t]);
        atomicAdd(&q.st[3 * D + t], ssq[0][t] + ssq[1][t] + ssq[2][t] + ssq[3][t]);
    }
    rel_barrier(bA + 1);

    // ---------------- stage 3: out = relu(bn2(z)) (f32) -----------------
    if (t < D) {
        float inv_n = 1.f / (float)q.N;
        float mean = ld_atomic(&q.st[2 * D + t]) * inv_n;
        float var = fmaxf(ld_atomic(&q.st[3 * D + t]) * inv_n - mean * mean, 0.f);
        float s = q.g2[t] * rsqrtf(var + BN_EPS);
        s_sc[t] = s;
        s_bi[t] = q.b2[t] - mean * s;
    }
    __syncthreads();
    const float sc0 = s_sc[2 * l], sc1 = s_sc[2 * l + 1];
    const float bi0 = s_bi[2 * l], bi1 = s_bi[2 * l + 1];
    for (int mt = 0; mt < MAXT; ++mt) {
        int tile = (int)blockIdx.x + mt * FUSE_GX;
        if (tile >= q.ntiles) break;
#pragma unroll
        for (int rr = 0; rr < 16; ++rr) {
            int row = w * 16 + rr;
            int grow = tile * 64 + row;
            if (grow >= q.N) break;
            int by = (((row << 8) + (l << 2)) ^ ((row & 7) << 4));
            unsigned u = *reinterpret_cast<const unsigned*>(yb + mt * 16384 + by);
            float2 o;
            o.x = fmaxf(fmaf(bflo(u), sc0, bi0), 0.f);
            o.y = fmaxf(fmaf(bfhi(u), sc1, bi1), 0.f);
            *reinterpret_cast<float2*>(q.out + (size_t)grow * D + 2 * l) = o;
        }
    }
}

// ---------------------------------------------------------------------------
extern "C" void kernel_launch(void* const* d_in, const int* in_sizes, int n_in,
                              void* d_out, int out_size, void* d_ws, size_t ws_size,
                              hipStream_t stream)
{
    const float* h_user   = (const float*)d_in[0];
    const float* h_item   = (const float*)d_in[1];
    const int* src_rates  = (const int*)d_in[2];
    const int* dst_rates  = (const int*)d_in[3];
    const int* src_rev    = (const int*)d_in[4];
    const int* dst_rev    = (const int*)d_in[5];
    const float* W1_rates = (const float*)d_in[6];
    const float* W2_rates = (const float*)d_in[7];
    const float* g1_rates = (const float*)d_in[8];
    const float* b1_rates = (const float*)d_in[9];
    const float* g2_rates = (const float*)d_in[10];
    const float* b2_rates = (const float*)d_in[11];
    const float* W1_rev   = (const float*)d_in[12];
    const float* W2_rev   = (const float*)d_in[13];
    const float* g1_rev   = (const float*)d_in[14];
    const float* b1_rev   = (const float*)d_in[15];
    const float* g2_rev   = (const float*)d_in[16];
    const float* b2_rev   = (const float*)d_in[17];

    const int n_user = in_sizes[0] / D;
    const int n_item = in_sizes[1] / D;
    const int E1 = in_sizes[2];
    const int E2 = in_sizes[4];

    const int bw4_0 = (n_item + 3) >> 2;
    const int bw4_1 = (n_user + 3) >> 2;

    char* p = (char*)d_ws;
    auto alloc = [&](size_t bytes) {
        char* q = p;
        p += (bytes + 255) & ~(size_t)255;
        return q;
    };
    unsigned short* hbu = (unsigned short*)alloc((size_t)n_user * D * 2);
    unsigned short* hbi = (unsigned short*)alloc((size_t)n_item * D * 2);
    unsigned short* xz0 = (unsigned short*)alloc((size_t)n_item * D * 2);
    unsigned short* xz1 = (unsigned short*)alloc((size_t)n_user * D * 2);
    unsigned short* wt  = (unsigned short*)alloc((size_t)4 * D * D * 2);
    float* stats   = (float*)alloc((size_t)8 * D * 4);
    int* bar       = (int*)alloc((size_t)8 * 4);
    int* counts0   = (int*)alloc((size_t)n_item * 4);
    int* counts1   = (int*)alloc((size_t)n_user * 4);
    int* offsets0  = (int*)alloc(((size_t)n_item + 1) * 4);
    int* offsets1  = (int*)alloc(((size_t)n_user + 1) * 4);
    int* bsum0     = (int*)alloc((size_t)64 * 4);
    int* bsum1     = (int*)alloc((size_t)64 * 4);
    int* perm0     = (int*)alloc((size_t)E1 * 4);
    int* perm1     = (int*)alloc((size_t)E2 * 4);
    unsigned char* rank0 = (unsigned char*)alloc((size_t)E1);
    unsigned char* rank1 = (unsigned char*)alloc((size_t)E2);
    unsigned* pc0  = (unsigned*)alloc((size_t)NCHF * bw4_0 * 4);
    unsigned* pc1  = (unsigned*)alloc((size_t)NCHF * bw4_1 * 4);

    float* out_user = (float*)d_out;
    float* out_item = out_user + (size_t)n_user * D;

    const int nu8 = n_user * D / 8, ni8 = n_item * D / 8;
    int pblocks = 65 + (nu8 + ni8 + 255) / 256;
    prep_kernel<<<pblocks, 256, 0, stream>>>(
        h_user, h_item, hbu, hbi, nu8, ni8,
        W1_rates, W2_rates, W1_rev, W2_rev, wt, stats, bar);

    float* st0 = stats;
    float* st1 = stats + 4 * D;

    CsrRel c0 = {src_rates, dst_rates, counts0, offsets0, bsum0, perm0,
                 rank0, pc0, E1, n_item, (n_item + 1023) / 1024};
    CsrRel c1 = {src_rev, dst_rev, counts1, offsets1, bsum1, perm1,
                 rank1, pc1, E2, n_user, (n_user + 1023) / 1024};

    int nmax = n_item > n_user ? n_item : n_user;
    int emax = E1 > E2 ? E1 : E2;
    int bw4m = bw4_0 > bw4_1 ? bw4_0 : bw4_1;
    int ns = c0.nscan > c1.nscan ? c0.nscan : c1.nscan;

    size_t hist_lds = (size_t)bw4m * 4;
    hist_kernel<<<dim3(NCHF, 2), 256, hist_lds, stream>>>(c0, c1);
    chunkpfx_kernel<<<dim3((bw4m + 255) / 256, 2), 256, 0, stream>>>(c0, c1);
    scan_offsets_kernel<<<dim3(ns, 2), 256, 0, stream>>>(c0, c1);
    int nfine = (emax + FILL_FINE - 1) / FILL_FINE;
    fill_kernel<<<dim3(NBUK * nfine, 2), 256, 0, stream>>>(c0, c1);

    GatherRel ga0 = {hbu, hbi, offsets0, perm0, xz0, n_item};
    GatherRel ga1 = {hbi, hbu, offsets1, perm1, xz1, n_user};
    int ab = (nmax + 3) / 4;
    gather_agg_kernel<<<dim3(ab, 2), 256, 0, stream>>>(ga0, ga1);

    // Fused MLP chain: one normal dispatch, fence-free capacity barrier.
    const int nt0 = (n_item + 63) / 64, nt1 = (n_user + 63) / 64;
    FusedRel f0 = {xz0, wt,             wt + (size_t)D * D,
                   g1_rates, b1_rates, g2_rates, b2_rates,
                   st0, out_item, n_item, nt0};
    FusedRel f1 = {xz1, wt + (size_t)2 * D * D, wt + (size_t)3 * D * D,
                   g1_rev, b1_rev, g2_rev, b2_rev,
                   st1, out_user, n_user, nt1};
    fused_mlp_kernel<<<dim3(FUSE_GX, 2), 256, 0, stream>>>(f0, f1, bar);
}